// Round 18
// baseline (373.756 us; speedup 1.0000x reference)
//
#include <hip/hip_runtime.h>
#include <hip/hip_bf16.h>

// Few-shot matching-network head + Conv4 backbone (MI355X, gfx950). Round 26.
//
// R25 (best, 366.8us): launch consolidation confirmed (~2.4us/launch; -5
// launches = -12us). R26 finishes it: (a) repack_w1m + repack_wm3 folded
// into the zero_all index-range mega-kernel (setup = probe + 1 kernel,
// -2 launches); (b) xform takes xs+xt and picks per-image by global index
// (straddling chunk: 2 calls -> 1, -1 launch); (c) proto+pnorm fused (each
// (b,c) block computes + normalizes its prototype row; kills a 737KB
// round-trip, -1 launch). All conv kernels byte-identical to R24/R25.
// Math identical r10-r25 (absmax 0.0039). If flat -> plateau.

#define BB 8
#define SS 25
#define TT 75
#define CC 5
#define DD 2304
#define NSUP 200
#define NTGT 600
#define NTOT 800
#define EPSF 1e-8f

// A1 plane layout constants
#define PLE 7744       // plane elems: 44*22*8
#define IMG1E 123904   // img elems: 16*7744

typedef __attribute__((ext_vector_type(8))) short bf16x8;
typedef __attribute__((ext_vector_type(4))) float f32x4;

__device__ __forceinline__ float load_ext(const void* p, size_t idx, int isf32) {
  if (isf32) return ((const float*)p)[idx];
  unsigned short u = ((const unsigned short*)p)[idx];
  union { unsigned int i; float f; } v;
  v.i = ((unsigned int)u) << 16;
  return v.f;
}

// Bijective XCD swizzle (R22, proven): contiguous logical range per XCD.
__device__ __forceinline__ int fsc_swz(int wg, int nwg) {
  const int q = nwg >> 3, r = nwg & 7;
  const int x = wg & 7, i = wg >> 3;
  return (x < r ? x * (q + 1) : r * (q + 1) + (x - r) * q) + i;
}

// ---- dtype probe (proven r3-r25): flag=1 => external data is fp32 ----
__global__ void fsc_probe_dtype_k(const unsigned short* __restrict__ w2raw,
                                  int nelems, int* __restrict__ flag) {
  __shared__ int cnt;
  if (threadIdx.x == 0) cnt = 0;
  __syncthreads();
  int local = 0;
  for (int i = threadIdx.x; i < nelems; i += 256) {
    unsigned short u = w2raw[i];
    int ex = (u >> 7) & 0xFF;
    if (ex != 0 && (ex < 0x69 || ex > 0x84)) local++;
  }
  atomicAdd(&cnt, local);
  __syncthreads();
  if (threadIdx.x == 0) *flag = (cnt > nelems / 8) ? 1 : 0;
}

// ---- R26 setup mega-kernel: index-range partition over
//      [0,4096): conv1 weight repack (r10 math)
//      [.., +3*36864): conv2/3/4 weight repack (r10 math, sel picks layer)
//      [.., +n1): X pads   [.., +n2): A1 pads
//      [.., +n3): A2 border<23>   [.., +n4): C3 border<13> ----
__global__ void fsc_setup_k(const void* __restrict__ W1s,
                            const void* __restrict__ W2s,
                            const void* __restrict__ W3s,
                            const void* __restrict__ W4s,
                            __hip_bfloat16* __restrict__ Wf1,
                            __hip_bfloat16* __restrict__ Wf2,
                            __hip_bfloat16* __restrict__ Wf3,
                            __hip_bfloat16* __restrict__ Wf4,
                            __hip_bfloat16* __restrict__ X,
                            __hip_bfloat16* __restrict__ A1,
                            __hip_bfloat16* __restrict__ A2,
                            __hip_bfloat16* __restrict__ C3,
                            int CHn, const int* __restrict__ flag) {
  const int isf32 = *flag;
  int i = blockIdx.x * blockDim.x + threadIdx.x;
  // -- conv1 weight repack --
  if (i < 4096) {
    int j = i & 7;
    int lane = (i >> 3) & 63;
    int t = (i >> 9) & 3;
    int s = i >> 11;
    int kk = (lane >> 4) * 8 + j;
    int co = t * 16 + (lane & 15);
    float v = 0.f;
    int kh, kwp, ci;
    bool live = false;
    if (s == 0) { kh = kk >> 4; kwp = (kk & 15) >> 2; ci = kk & 3; live = true; }
    else if (kk < 16) { kh = 2; kwp = kk >> 2; ci = kk & 3; live = true; }
    if (live && kwp < 3 && ci < 3)
      v = load_ext(W1s, (size_t)((co * 3 + ci) * 3 + kh) * 3 + kwp, isf32);
    Wf1[i] = __float2bfloat16(v);
    return;
  }
  i -= 4096;
  // -- conv2/3/4 weight repack --
  if (i < 3 * 36864) {
    const int sel = i / 36864;
    const int o = i - sel * 36864;
    const void* W = sel == 0 ? W2s : (sel == 1 ? W3s : W4s);
    __hip_bfloat16* Wf = sel == 0 ? Wf2 : (sel == 1 ? Wf3 : Wf4);
    int j = o & 7;
    int lane = (o >> 3) & 63;
    int t = (o >> 9) & 3;
    int kk = o >> 11;       // 0..17
    int s = kk & 1;
    int khw = kk >> 1;      // kh*3+kw
    int kh = khw / 3, kw = khw - kh * 3;
    int co = t * 16 + (lane & 15);
    int ci = s * 32 + (lane >> 4) * 8 + j;
    float v = load_ext(W, (size_t)((co * 64 + ci) * 3 + kh) * 3 + kw, isf32);
    Wf[o] = __float2bfloat16(v);
    return;
  }
  i -= 3 * 36864;
  const int n1 = CHn * 1360;
  const int n2 = CHn * 11008;
  const int n3 = CHn * (4 * 23 - 4) * 64;
  const int n4 = NTOT * (4 * 13 - 4) * 64;
  if (i < n1) {
    // X pads: rows 84..85 (all w) + cols 84..85 (h<84), 4 ch
    int c = i & 3;
    int p = (i >> 2) % 340;
    int n = (i >> 2) / 340;
    int h, w;
    if (p < 172) { h = 84 + (p / 86); w = p % 86; }
    else { int pp = p - 172; h = pp >> 1; w = 84 + (pp & 1); }
    X[(((size_t)n * 86 + h) * 86 + w) * 4 + c] = __float2bfloat16(0.f);
    return;
  }
  i -= n1;
  if (i < n2) {
    // A1 plane pads
    int ch = i & 7;
    int q = (i >> 3) % 86;
    int pl = ((i >> 3) / 86) % 16;
    int n = (i >> 3) / (86 * 16);
    const int wp = pl & 1;
    int h, w2;
    if (q < 22) { h = 0; w2 = q; }
    else if (q < 44) { h = 43; w2 = q - 22; }
    else { h = q - 43; w2 = wp ? 21 : 0; }  // h = 1..42
    A1[(size_t)n * IMG1E + pl * PLE + (h * 22 + w2) * 8 + ch] = __float2bfloat16(0.f);
    return;
  }
  i -= n2;
  if (i < n3) {
    constexpr int P = 23;
    const int RP = 4 * P - 4;
    int c = i & 63;
    int r = (i >> 6) % RP;
    int n = (i >> 6) / RP;
    int row, colp;
    if (r < P) { row = 0; colp = r; }
    else if (r < 2 * P) { row = P - 1; colp = r - P; }
    else if (r < 3 * P - 2) { row = r - 2 * P + 1; colp = 0; }
    else { row = r - (3 * P - 2) + 1; colp = P - 1; }
    A2[(((size_t)n * P + row) * P + colp) * 64 + c] = __float2bfloat16(0.f);
    return;
  }
  i -= n3;
  if (i < n4) {
    constexpr int P = 13;
    const int RP = 4 * P - 4;
    int c = i & 63;
    int r = (i >> 6) % RP;
    int n = (i >> 6) / RP;
    int row, colp;
    if (r < P) { row = 0; colp = r; }
    else if (r < 2 * P) { row = P - 1; colp = r - P; }
    else if (r < 3 * P - 2) { row = r - 2 * P + 1; colp = 0; }
    else { row = r - (3 * P - 2) + 1; colp = P - 1; }
    C3[(((size_t)n * P + row) * P + colp) * 64 + c] = __float2bfloat16(0.f);
  }
}

// ---- R26 input transform, dual-source: picks xs/xt by GLOBAL img index.
//      Same per-element math as r10-r25 xform1. One call per chunk. ----
__global__ void fsc_xform1b_k(const void* __restrict__ xs,
                              const void* __restrict__ xt, int g0,
                              __hip_bfloat16* __restrict__ X,
                              int n, const int* __restrict__ flag) {
  const int isf32 = *flag;
  int i = blockIdx.x * blockDim.x + threadIdx.x;
  const int imgL = i / 7056;
  if (imgL >= n) return;
  const int sp = i - imgL * 7056;
  const int h = sp / 84, w = sp - h * 84;
  const int g = g0 + imgL;
  const void* src = g < NSUP ? xs : xt;
  const size_t base = (size_t)(g < NSUP ? g : g - NSUP) * 21168;
  union { unsigned short u[4]; uint2 q; } pk;
#pragma unroll
  for (int ci = 0; ci < 3; ++ci)
    pk.u[ci] = __bfloat16_as_ushort(__float2bfloat16(load_ext(src, base + ci * 7056 + sp, isf32)));
  pk.u[3] = 0;
  *(uint2*)(void*)(X + (((size_t)imgL * 86 + h) * 86 + w) * 4) = pk.q;
}

// ---- conv1 MFMA (NHWC4 input; proven r10), epilogue -> A1 PLANE layout.
//      R14 form (8KB LDS weights) + XCD swizzle (R22). ----
__global__ void fsc_conv1m_k(const __hip_bfloat16* __restrict__ X,
                             const __hip_bfloat16* __restrict__ Wf,
                             const void* __restrict__ bias,
                             __hip_bfloat16* __restrict__ out, int N,
                             const int* __restrict__ flag) {
  __shared__ uint4 sW4[512];  // 8 KB: [s=2][t=4][lane=64][j=8] bf16
  {
    const uint4* s = (const uint4*)(const void*)Wf;
#pragma unroll
    for (int i = 0; i < 2; ++i) sW4[threadIdx.x + 256 * i] = s[threadIdx.x + 256 * i];
  }
  __syncthreads();
  const __hip_bfloat16* sW = (const __hip_bfloat16*)sW4;

  constexpr int TPI = 28;  // ceil(1764/64)
  const int wid = fsc_swz(blockIdx.x, gridDim.x) * 4 + (threadIdx.x >> 6);
  const int img = wid / TPI;
  if (img >= N) return;
  const int tl = wid - img * TPI;
  const int lane = threadIdx.x & 63;
  const int nidx = lane & 15, quad = lane >> 4;

  int col[4];
  bool val[4];
  int hoA[4], woA[4];
#pragma unroll
  for (int p = 0; p < 4; ++p) {
    col[p] = tl * 64 + p * 16 + nidx;
    val[p] = col[p] < 1764;
    if (!val[p]) col[p] = 1763;
    hoA[p] = col[p] / 42;
    woA[p] = col[p] - hoA[p] * 42;
  }

  f32x4 acc[4][4];
#pragma unroll
  for (int p = 0; p < 4; ++p)
#pragma unroll
    for (int t = 0; t < 4; ++t) acc[p][t] = (f32x4){0.f, 0.f, 0.f, 0.f};

#pragma unroll
  for (int s = 0; s < 2; ++s) {
    bf16x8 b[4];
#pragma unroll
    for (int p = 0; p < 4; ++p) {
      const int hi = 2 * hoA[p] + (s == 0 ? (quad >> 1) : 2);
      const __hip_bfloat16* bp =
          X + (((size_t)img * 86 + hi) * 86 + 2 * woA[p]) * 4 + (quad & 1) * 8;
      b[p] = *(const bf16x8*)(const void*)bp;
    }
#pragma unroll
    for (int t = 0; t < 4; ++t) {
      bf16x8 a = *(const bf16x8*)(const void*)(sW + ((size_t)(s * 4 + t) * 64 + lane) * 8);
#pragma unroll
      for (int p = 0; p < 4; ++p)
        acc[p][t] = __builtin_amdgcn_mfma_f32_16x16x32_bf16(a, b[p], acc[p][t], 0, 0, 0);
    }
  }

  const int isf32 = *flag;
#pragma unroll
  for (int p = 0; p < 4; ++p) {
    const int h = hoA[p] + 1;
    const int wq = woA[p] + 1;
    const int wp = wq & 1, w2 = wq >> 1;
#pragma unroll
    for (int t = 0; t < 4; ++t) {
      float v[4];
#pragma unroll
      for (int r = 0; r < 4; ++r) {
        const int cout = t * 16 + quad * 4 + r;
        float xv = acc[p][t][r] + load_ext(bias, cout, isf32);
        v[r] = xv > 0.f ? xv : 0.f;
      }
      if (val[p]) {
        // plane = cg*2+wp, cg = 2t + (quad>>1); within-pixel ch = (quad&1)*4
        __hip_bfloat16* o = out + (size_t)img * IMG1E +
                            ((2 * t + (quad >> 1)) * 2 + wp) * PLE +
                            (h * 22 + w2) * 8 + (quad & 1) * 4;
        union { unsigned short u[4]; uint2 w; } pk;
#pragma unroll
        for (int r = 0; r < 4; ++r) pk.u[r] = __bfloat16_as_ushort(__float2bfloat16(v[r]));
        *(uint2*)(void*)o = pk.w;
      }
    }
  }
}

// ---- conv2 from A1 planes: 32 cols x 64 couts, depth-4 B prefetch.
//      R14 form + XCD swizzle + chunk residency (proven r22-r25). ----
__global__ void fsc_conv2p_k(const __hip_bfloat16* __restrict__ A1,
                             const __hip_bfloat16* __restrict__ Wf,
                             const void* __restrict__ bias,
                             __hip_bfloat16* __restrict__ out, int N,
                             const int* __restrict__ flag) {
  __shared__ uint4 sW4[4608];  // 72 KB
  {
    const uint4* s = (const uint4*)(const void*)Wf;
#pragma unroll
    for (int i = 0; i < 18; ++i) sW4[threadIdx.x + 256 * i] = s[threadIdx.x + 256 * i];
  }
  __syncthreads();
  const __hip_bfloat16* sW = (const __hip_bfloat16*)sW4;

  constexpr int TPI = 14;  // ceil(441/32)
  const int wid = fsc_swz(blockIdx.x, gridDim.x) * 4 + (threadIdx.x >> 6);
  const int img = wid / TPI;
  if (img >= N) return;
  const int tl = wid - img * TPI;
  const int lane = threadIdx.x & 63;
  const int nidx = lane & 15, quad = lane >> 4;

  int col[2];
  bool val[2];
  int hoA[2], woA[2];
  const __hip_bfloat16* bsrc[2];
#pragma unroll
  for (int p = 0; p < 2; ++p) {
    col[p] = tl * 32 + p * 16 + nidx;
    val[p] = col[p] < 441;
    if (!val[p]) col[p] = 440;
    hoA[p] = col[p] / 21;
    woA[p] = col[p] - hoA[p] * 21;
    // base: img + quad's cg-pair + input row (2ho+1) + col w2=wo
    bsrc[p] = A1 + (size_t)img * IMG1E + quad * (2 * PLE) +
              ((2 * hoA[p] + 1) * 22 + woA[p]) * 8;
  }
  const __hip_bfloat16* asrc = sW + lane * 8;

  f32x4 acc[2][4];
#pragma unroll
  for (int p = 0; p < 2; ++p)
#pragma unroll
    for (int t = 0; t < 4; ++t) acc[p][t] = (f32x4){0.f, 0.f, 0.f, 0.f};

  // offset(kk): s=kk&1, kh=(kk>>1)/3, kw=(kk>>1)%3
#define FSC_BOFF2(kk)                                                        \
  ((((kk)&1) * 8 + ((1 + (((kk) >> 1) % 3)) & 1)) * PLE +                    \
   (((((kk) >> 1)) / 3) * 22 + ((1 + (((kk) >> 1) % 3)) >> 1)) * 8)

  bf16x8 bbuf[4][2];
#pragma unroll
  for (int d = 0; d < 3; ++d)
#pragma unroll
    for (int p = 0; p < 2; ++p)
      bbuf[d][p] = *(const bf16x8*)(const void*)(bsrc[p] + FSC_BOFF2(d));

#pragma unroll
  for (int kk = 0; kk < 18; ++kk) {
    if (kk + 3 < 18) {
#pragma unroll
      for (int p = 0; p < 2; ++p)
        bbuf[(kk + 3) & 3][p] =
            *(const bf16x8*)(const void*)(bsrc[p] + FSC_BOFF2(kk + 3));
    }
#pragma unroll
    for (int t = 0; t < 4; ++t) {
      bf16x8 a = *(const bf16x8*)(const void*)(asrc + (kk * 4 + t) * 512);
#pragma unroll
      for (int p = 0; p < 2; ++p)
        acc[p][t] =
            __builtin_amdgcn_mfma_f32_16x16x32_bf16(a, bbuf[kk & 3][p], acc[p][t], 0, 0, 0);
    }
  }
#undef FSC_BOFF2

  const int isf32 = *flag;
#pragma unroll
  for (int p = 0; p < 2; ++p) {
#pragma unroll
    for (int t = 0; t < 4; ++t) {
      float v[4];
#pragma unroll
      for (int r = 0; r < 4; ++r) {
        const int cout = t * 16 + quad * 4 + r;
        float xv = acc[p][t][r] + load_ext(bias, cout, isf32);
        v[r] = xv > 0.f ? xv : 0.f;
      }
      if (val[p]) {
        __hip_bfloat16* o = out + (((size_t)img * 23 + (hoA[p] + 1)) * 23 +
                                   (woA[p] + 1)) * 64 + t * 16 + quad * 4;
        union { unsigned short u[4]; uint2 w; } pk;
#pragma unroll
        for (int r = 0; r < 4; ++r) pk.u[r] = __bfloat16_as_ushort(__float2bfloat16(v[r]));
        *(uint2*)(void*)o = pk.w;
      }
    }
  }
}

// ---- implicit-GEMM conv, CG*16 cols x 64 couts, depth-4 B prefetch.
//      R14 form (72KB LDS) + XCD swizzle (R22). ----
template <int HO, int PWI, int PWO, int ROFF, int CG>
__global__ void fsc_convp_k(const __hip_bfloat16* __restrict__ in,
                            const __hip_bfloat16* __restrict__ Wf,
                            const void* __restrict__ bias,
                            __hip_bfloat16* __restrict__ out, int N,
                            const int* __restrict__ flag) {
  __shared__ uint4 sW4[4608];  // 72 KB
  {
    const uint4* s = (const uint4*)(const void*)Wf;
#pragma unroll
    for (int i = 0; i < 18; ++i) sW4[threadIdx.x + 256 * i] = s[threadIdx.x + 256 * i];
  }
  __syncthreads();
  const __hip_bfloat16* sW = (const __hip_bfloat16*)sW4;

  constexpr int COLS = CG * 16;
  constexpr int TPI = (HO * HO + COLS - 1) / COLS;
  const int wid = fsc_swz(blockIdx.x, gridDim.x) * 4 + (threadIdx.x >> 6);
  const int img = wid / TPI;
  if (img >= N) return;
  const int tl = wid - img * TPI;
  const int lane = threadIdx.x & 63;
  const int nidx = lane & 15, quad = lane >> 4;

  int col[CG];
  bool val[CG];
  int hoA[CG], woA[CG];
  const __hip_bfloat16* bsrc[CG];
#pragma unroll
  for (int p = 0; p < CG; ++p) {
    col[p] = tl * COLS + p * 16 + nidx;
    val[p] = col[p] < HO * HO;
    if (!val[p]) col[p] = HO * HO - 1;
    hoA[p] = col[p] / HO;
    woA[p] = col[p] - hoA[p] * HO;
    bsrc[p] = in + (((size_t)img * PWI + (2 * hoA[p] + ROFF)) * PWI +
                    (2 * woA[p] + ROFF)) * 64 + quad * 8;
  }
  const __hip_bfloat16* asrc = sW + lane * 8;

  f32x4 acc[CG][4];
#pragma unroll
  for (int p = 0; p < CG; ++p)
#pragma unroll
    for (int t = 0; t < 4; ++t) acc[p][t] = (f32x4){0.f, 0.f, 0.f, 0.f};

#define FSC_BOFF(kk) ((((kk) >> 1) / 3 * PWI + ((kk) >> 1) % 3) * 64 + ((kk)&1) * 32)

  bf16x8 bbuf[4][CG];
#pragma unroll
  for (int d = 0; d < 3; ++d)
#pragma unroll
    for (int p = 0; p < CG; ++p)
      bbuf[d][p] = *(const bf16x8*)(const void*)(bsrc[p] + FSC_BOFF(d));

#pragma unroll
  for (int kk = 0; kk < 18; ++kk) {
    if (kk + 3 < 18) {
#pragma unroll
      for (int p = 0; p < CG; ++p)
        bbuf[(kk + 3) & 3][p] =
            *(const bf16x8*)(const void*)(bsrc[p] + FSC_BOFF(kk + 3));
    }
#pragma unroll
    for (int t = 0; t < 4; ++t) {
      bf16x8 a = *(const bf16x8*)(const void*)(asrc + (kk * 4 + t) * 512);
#pragma unroll
      for (int p = 0; p < CG; ++p)
        acc[p][t] =
            __builtin_amdgcn_mfma_f32_16x16x32_bf16(a, bbuf[kk & 3][p], acc[p][t], 0, 0, 0);
    }
  }
#undef FSC_BOFF

  const int isf32 = *flag;
#pragma unroll
  for (int p = 0; p < CG; ++p) {
#pragma unroll
    for (int t = 0; t < 4; ++t) {
      float v[4];
#pragma unroll
      for (int r = 0; r < 4; ++r) {
        const int cout = t * 16 + quad * 4 + r;
        float xv = acc[p][t][r] + load_ext(bias, cout, isf32);
        v[r] = xv > 0.f ? xv : 0.f;
      }
      if (val[p]) {
        __hip_bfloat16* o = out + (((size_t)img * PWO + (hoA[p] + 1)) * PWO +
                                   (woA[p] + 1)) * 64 + t * 16 + quad * 4;
        union { unsigned short u[4]; uint2 w; } pk;
#pragma unroll
        for (int r = 0; r < 4; ++r) pk.u[r] = __bfloat16_as_ushort(__float2bfloat16(v[r]));
        *(uint2*)(void*)o = pk.w;
      }
    }
  }
}

// ---- 32-col MFMA conv, EMB output (conv4). R14 form + XCD swizzle. ----
__global__ void fsc_conv4_k(const __hip_bfloat16* __restrict__ in,
                            const __hip_bfloat16* __restrict__ Wf,
                            const void* __restrict__ bias, float* __restrict__ emb,
                            int N, const int* __restrict__ flag) {
  __shared__ uint4 sW4[4608];  // 72 KB
  {
    const uint4* s = (const uint4*)(const void*)Wf;
#pragma unroll
    for (int i = 0; i < 18; ++i) sW4[threadIdx.x + 256 * i] = s[threadIdx.x + 256 * i];
  }
  __syncthreads();
  const __hip_bfloat16* sW = (const __hip_bfloat16*)sW4;

  constexpr int HO = 6, PWI = 13;
  constexpr int TPI = 2;  // ceil(36/32)
  const int wid = fsc_swz(blockIdx.x, gridDim.x) * 4 + (threadIdx.x >> 6);
  const int img = wid / TPI;
  if (img >= N) return;
  const int tl = wid - img * TPI;
  const int lane = threadIdx.x & 63;
  const int nidx = lane & 15, quad = lane >> 4;

  int col0 = tl * 32 + nidx;
  int col1 = col0 + 16;
  const bool val0 = col0 < HO * HO;
  const bool val1 = col1 < HO * HO;
  if (!val0) col0 = HO * HO - 1;
  if (!val1) col1 = HO * HO - 1;
  const int ho0 = col0 / HO, wo0 = col0 - ho0 * HO;
  const int ho1 = col1 / HO, wo1 = col1 - ho1 * HO;

  const __hip_bfloat16* bsrc0 =
      in + (((size_t)img * PWI + 2 * ho0) * PWI + 2 * wo0) * 64 + quad * 8;
  const __hip_bfloat16* bsrc1 =
      in + (((size_t)img * PWI + 2 * ho1) * PWI + 2 * wo1) * 64 + quad * 8;
  const __hip_bfloat16* asrc = sW + lane * 8;

  f32x4 acc[2][4];
#pragma unroll
  for (int p = 0; p < 2; ++p)
#pragma unroll
    for (int t = 0; t < 4; ++t) acc[p][t] = (f32x4){0.f, 0.f, 0.f, 0.f};

#pragma unroll
  for (int kk = 0; kk < 18; ++kk) {
    const int s = kk & 1;
    const int khw = kk >> 1;
    const int kh = khw / 3, kw = khw - kh * 3;
    const int boff = (kh * PWI + kw) * 64 + s * 32;
    bf16x8 b0 = *(const bf16x8*)(const void*)(bsrc0 + boff);
    bf16x8 b1 = *(const bf16x8*)(const void*)(bsrc1 + boff);
#pragma unroll
    for (int t = 0; t < 4; ++t) {
      bf16x8 a = *(const bf16x8*)(const void*)(asrc + (kk * 4 + t) * 512);
      acc[0][t] = __builtin_amdgcn_mfma_f32_16x16x32_bf16(a, b0, acc[0][t], 0, 0, 0);
      acc[1][t] = __builtin_amdgcn_mfma_f32_16x16x32_bf16(a, b1, acc[1][t], 0, 0, 0);
    }
  }

  const int isf32 = *flag;
#pragma unroll
  for (int p = 0; p < 2; ++p) {
    const bool valid = p == 0 ? val0 : val1;
    const int col = p == 0 ? col0 : col1;
#pragma unroll
    for (int t = 0; t < 4; ++t) {
      float v[4];
#pragma unroll
      for (int r = 0; r < 4; ++r) {
        const int cout = t * 16 + quad * 4 + r;
        float xv = acc[p][t][r] + load_ext(bias, cout, isf32);
        v[r] = xv > 0.f ? xv : 0.f;
      }
      if (valid) {
        float* o = emb + ((size_t)img * 36 + col) * 64 + t * 16 + quad * 4;
        *(f32x4*)(void*)o = (f32x4){v[0], v[1], v[2], v[3]};
      }
    }
  }
}

// ---- R26 head: proto+pnorm FUSED. One block per (b,c): compute proto row
//      (sum over class-matching supports x0.2, same fp32 order as r3-r25),
//      block-reduce sumsq, normalize, write pn. protos round-trip gone. ----
__global__ void fsc_protonorm_k(const float* __restrict__ emb_s,
                                const int* __restrict__ y,
                                float* __restrict__ pn) {
  __shared__ float red[4];
  __shared__ float inv;
  const int bc = blockIdx.x;
  const int c = bc % CC;
  const int b = bc / CC;
  float pr[9];
  float ss = 0.f;
#pragma unroll
  for (int k = 0; k < 9; ++k) {
    const int d = threadIdx.x + 256 * k;
    float sum = 0.f;
    for (int s = 0; s < SS; ++s) {
      if (y[b * SS + s] % CC == c) sum += emb_s[(size_t)(b * SS + s) * DD + d];
    }
    pr[k] = sum * 0.2f;
    ss += pr[k] * pr[k];
  }
#pragma unroll
  for (int off = 32; off > 0; off >>= 1) ss += __shfl_down(ss, off);
  if ((threadIdx.x & 63) == 0) red[threadIdx.x >> 6] = ss;
  __syncthreads();
  if (threadIdx.x == 0) {
    float nrm = sqrtf(red[0] + red[1] + red[2] + red[3]);
    nrm = nrm > EPSF ? nrm : EPSF;
    inv = 1.f / nrm;
  }
  __syncthreads();
  const float sc = inv;
#pragma unroll
  for (int k = 0; k < 9; ++k)
    pn[(size_t)bc * DD + threadIdx.x + 256 * k] = pr[k] * sc;
}

__global__ void fsc_preds_k(const float* __restrict__ emb_t, const float* __restrict__ pn,
                            void* __restrict__ out, const int* __restrict__ flag) {
  __shared__ float red[4][6];
  __shared__ float fin[6];
  const int isf32 = *flag;
  const int bt = blockIdx.x;
  const int b = bt / TT;
  const float* et = emb_t + (size_t)bt * DD;
  float e[9];
#pragma unroll
  for (int k = 0; k < 9; ++k) e[k] = et[threadIdx.x + 256 * k];
  float vals[6];
  {
    float ss = 0.f;
#pragma unroll
    for (int k = 0; k < 9; ++k) ss += e[k] * e[k];
    vals[0] = ss;
  }
  const float* pb = pn + (size_t)b * CC * DD;
#pragma unroll
  for (int c = 0; c < CC; ++c) {
    float s = 0.f;
#pragma unroll
    for (int k = 0; k < 9; ++k) s += e[k] * pb[(size_t)c * DD + threadIdx.x + 256 * k];
    vals[1 + c] = s;
  }
#pragma unroll
  for (int v = 0; v < 6; ++v) {
#pragma unroll
    for (int off = 32; off > 0; off >>= 1) vals[v] += __shfl_down(vals[v], off);
  }
  if ((threadIdx.x & 63) == 0) {
#pragma unroll
    for (int v = 0; v < 6; ++v) red[threadIdx.x >> 6][v] = vals[v];
  }
  __syncthreads();
  if (threadIdx.x < 6)
    fin[threadIdx.x] = red[0][threadIdx.x] + red[1][threadIdx.x] +
                       red[2][threadIdx.x] + red[3][threadIdx.x];
  __syncthreads();
  if (threadIdx.x < CC) {
    float nt = sqrtf(fin[0]);
    nt = nt > EPSF ? nt : EPSF;
    float r = fin[1 + threadIdx.x] / nt;
    if (isf32) ((float*)out)[(size_t)bt * CC + threadIdx.x] = r;
    else ((__hip_bfloat16*)out)[(size_t)bt * CC + threadIdx.x] = __float2bfloat16(r);
  }
}

static inline int fsc_cdiv(int a, int b) { return (a + b - 1) / b; }
static inline int imin(int a, int b) { return a < b ? a : b; }

extern "C" void kernel_launch(void* const* d_in, const int* in_sizes, int n_in,
                              void* d_out, int out_size, void* d_ws, size_t ws_size,
                              hipStream_t stream) {
  const void* xs = d_in[0];
  const void* xt = d_in[1];
  const int* y = (const int*)d_in[2];
  const void* W1 = d_in[3];
  const void* b1 = d_in[4];
  const void* W2 = d_in[5];
  const void* b2 = d_in[6];
  const void* W3 = d_in[7];
  const void* b3 = d_in[8];
  const void* W4 = d_in[9];
  const void* b4 = d_in[10];

  // ---- workspace layout: fixed ~25.6 MB + X/A1/A2 chunk buffers ----
  char* w = (char*)d_ws;
  int* flag = (int*)w;                      w += 256;
  __hip_bfloat16* Wf1 = (__hip_bfloat16*)w; w += 4096 * 2;
  __hip_bfloat16* Wf2 = (__hip_bfloat16*)w; w += 36864 * 2;
  __hip_bfloat16* Wf3 = (__hip_bfloat16*)w; w += 36864 * 2;
  __hip_bfloat16* Wf4 = (__hip_bfloat16*)w; w += 36864 * 2;
  float* pn = (float*)w;                    w += (size_t)BB * CC * DD * 4;
  float* emb = (float*)w;                   w += (size_t)NTOT * DD * 4;           // 7.37 MB
  __hip_bfloat16* C3 = (__hip_bfloat16*)w;  w += (size_t)NTOT * 13 * 13 * 64 * 2; // 17.3 MB
  char* chunk0 = w;
  const size_t fixedB = (size_t)(w - (char*)d_ws);
  const size_t szX  = (size_t)86 * 86 * 4 * 2;    //  59,168 B/img
  const size_t szA1 = (size_t)IMG1E * 2;          // 247,808 B/img (plane layout)
  const size_t szA2 = (size_t)23 * 23 * 64 * 2;   //  67,712 B/img
  const size_t perImgB = szX + szA1 + szA2;        // 374,688 B/img

  // R24: CH=400 — residency preserved (A1 99MB; working set ~170MB < L3)
  // while conv3 grid fills (800 WGs = 3.1/CU) and chunk launches halve.
  int CH = 50;
  const int cands[4] = {400, 200, 100, 50};
  for (int k = 0; k < 4; ++k) {
    if (fixedB + (size_t)cands[k] * perImgB <= ws_size) { CH = cands[k]; break; }
  }
  __hip_bfloat16* X  = (__hip_bfloat16*)chunk0;
  __hip_bfloat16* A1 = (__hip_bfloat16*)(chunk0 + (size_t)CH * szX);
  __hip_bfloat16* A2 = (__hip_bfloat16*)(chunk0 + (size_t)CH * (szX + szA1));

  // 1. dtype probe + setup mega-kernel (repacks + pad zeroing merged)
  fsc_probe_dtype_k<<<1, 256, 0, stream>>>((const unsigned short*)W2, 64 * 64 * 9, flag);
  {
    const int nz = 4096 + 3 * 36864 + CH * 1360 + CH * 11008 +
                   CH * (4 * 23 - 4) * 64 + NTOT * (4 * 13 - 4) * 64;
    fsc_setup_k<<<fsc_cdiv(nz, 256), 256, 0, stream>>>(
        W1, W2, W3, W4, Wf1, Wf2, Wf3, Wf4, X, A1, A2, C3, CH, flag);
  }

  // 2. chunks over GLOBAL image index (support 0..199, target 200..799)
  for (int g0 = 0; g0 < NTOT; g0 += CH) {
    const int n = imin(CH, NTOT - g0);
    // input transform (dual-source, one call per chunk)
    fsc_xform1b_k<<<fsc_cdiv(n * 7056, 256), 256, 0, stream>>>(
        xs, xt, g0, X, n, flag);
    // conv1: NHWC4 -> A1 planes; TPI=28
    fsc_conv1m_k<<<fsc_cdiv(n * 28, 4), 256, 0, stream>>>(X, Wf1, b1, A1, n, flag);
    // conv2: A1 planes -> 21x21 into 23-pad NHWC; 32 cols (TPI=14)
    fsc_conv2p_k<<<fsc_cdiv(n * 14, 4), 256, 0, stream>>>(A1, Wf2, b2, A2, n, flag);
    // conv3: 23-pad -> 11x11 into 13-pad; ROFF=0; 16 cols (TPI=8)
    fsc_convp_k<11, 23, 13, 0, 1><<<fsc_cdiv(n * 8, 4), 256, 0, stream>>>(
        A2, Wf3, b3, C3 + (size_t)g0 * 13 * 13 * 64, n, flag);
  }

  // 3. conv4 full batch: 13-pad -> fp32 emb [800][2304]
  fsc_conv4_k<<<fsc_cdiv(NTOT * 2, 4), 256, 0, stream>>>(C3, Wf4, b4, emb, NTOT, flag);

  // 4. head (proto+pnorm fused)
  fsc_protonorm_k<<<BB * CC, 256, 0, stream>>>(emb, y, pn);
  fsc_preds_k<<<NTGT, 256, 0, stream>>>(emb + (size_t)NSUP * DD, pn, d_out, flag);
}

// Round 20
// 359.066 us; speedup vs baseline: 1.0409x; 1.0409x over previous
//
#include <hip/hip_runtime.h>
#include <hip/hip_bf16.h>

// Few-shot matching-network head + Conv4 backbone (MI355X, gfx950). Round 27b.
// (R27 resubmission — Round 19 failed with GPUAcquisitionTimeout, kernel
// never ran.)
//
// R26 (373.8us) regressed vs R25 (366.8): of its 3 merges, the proto+pnorm
// fusion dropped head occupancy 360->40 blocks (0.16/CU) on the 9.2MB
// emb_s read — latency-bound underfill, ~10us cost, eating the ~5us launch
// savings. R27 = single-variable rollback: KEEP setup mega-kernel + dual-
// source xform (sound, -3 launches), REVERT head to R25's separate
// proto_k(360 blk)+pnorm_k(40 blk). All conv kernels byte-identical to
// R22-R26. Math identical r10-r26 (absmax 0.0039).
// Falsifier: >=370 -> mega-kernel/xform at fault -> full R25 revert.

#define BB 8
#define SS 25
#define TT 75
#define CC 5
#define DD 2304
#define NSUP 200
#define NTGT 600
#define NTOT 800
#define EPSF 1e-8f

// A1 plane layout constants
#define PLE 7744       // plane elems: 44*22*8
#define IMG1E 123904   // img elems: 16*7744

typedef __attribute__((ext_vector_type(8))) short bf16x8;
typedef __attribute__((ext_vector_type(4))) float f32x4;

__device__ __forceinline__ float load_ext(const void* p, size_t idx, int isf32) {
  if (isf32) return ((const float*)p)[idx];
  unsigned short u = ((const unsigned short*)p)[idx];
  union { unsigned int i; float f; } v;
  v.i = ((unsigned int)u) << 16;
  return v.f;
}

// Bijective XCD swizzle (R22, proven): contiguous logical range per XCD.
__device__ __forceinline__ int fsc_swz(int wg, int nwg) {
  const int q = nwg >> 3, r = nwg & 7;
  const int x = wg & 7, i = wg >> 3;
  return (x < r ? x * (q + 1) : r * (q + 1) + (x - r) * q) + i;
}

// ---- dtype probe (proven r3-r26): flag=1 => external data is fp32 ----
__global__ void fsc_probe_dtype_k(const unsigned short* __restrict__ w2raw,
                                  int nelems, int* __restrict__ flag) {
  __shared__ int cnt;
  if (threadIdx.x == 0) cnt = 0;
  __syncthreads();
  int local = 0;
  for (int i = threadIdx.x; i < nelems; i += 256) {
    unsigned short u = w2raw[i];
    int ex = (u >> 7) & 0xFF;
    if (ex != 0 && (ex < 0x69 || ex > 0x84)) local++;
  }
  atomicAdd(&cnt, local);
  __syncthreads();
  if (threadIdx.x == 0) *flag = (cnt > nelems / 8) ? 1 : 0;
}

// ---- R26 setup mega-kernel (kept): repacks + pad zeroing, index ranges ----
__global__ void fsc_setup_k(const void* __restrict__ W1s,
                            const void* __restrict__ W2s,
                            const void* __restrict__ W3s,
                            const void* __restrict__ W4s,
                            __hip_bfloat16* __restrict__ Wf1,
                            __hip_bfloat16* __restrict__ Wf2,
                            __hip_bfloat16* __restrict__ Wf3,
                            __hip_bfloat16* __restrict__ Wf4,
                            __hip_bfloat16* __restrict__ X,
                            __hip_bfloat16* __restrict__ A1,
                            __hip_bfloat16* __restrict__ A2,
                            __hip_bfloat16* __restrict__ C3,
                            int CHn, const int* __restrict__ flag) {
  const int isf32 = *flag;
  int i = blockIdx.x * blockDim.x + threadIdx.x;
  // -- conv1 weight repack --
  if (i < 4096) {
    int j = i & 7;
    int lane = (i >> 3) & 63;
    int t = (i >> 9) & 3;
    int s = i >> 11;
    int kk = (lane >> 4) * 8 + j;
    int co = t * 16 + (lane & 15);
    float v = 0.f;
    int kh, kwp, ci;
    bool live = false;
    if (s == 0) { kh = kk >> 4; kwp = (kk & 15) >> 2; ci = kk & 3; live = true; }
    else if (kk < 16) { kh = 2; kwp = kk >> 2; ci = kk & 3; live = true; }
    if (live && kwp < 3 && ci < 3)
      v = load_ext(W1s, (size_t)((co * 3 + ci) * 3 + kh) * 3 + kwp, isf32);
    Wf1[i] = __float2bfloat16(v);
    return;
  }
  i -= 4096;
  // -- conv2/3/4 weight repack --
  if (i < 3 * 36864) {
    const int sel = i / 36864;
    const int o = i - sel * 36864;
    const void* W = sel == 0 ? W2s : (sel == 1 ? W3s : W4s);
    __hip_bfloat16* Wf = sel == 0 ? Wf2 : (sel == 1 ? Wf3 : Wf4);
    int j = o & 7;
    int lane = (o >> 3) & 63;
    int t = (o >> 9) & 3;
    int kk = o >> 11;       // 0..17
    int s = kk & 1;
    int khw = kk >> 1;      // kh*3+kw
    int kh = khw / 3, kw = khw - kh * 3;
    int co = t * 16 + (lane & 15);
    int ci = s * 32 + (lane >> 4) * 8 + j;
    float v = load_ext(W, (size_t)((co * 64 + ci) * 3 + kh) * 3 + kw, isf32);
    Wf[o] = __float2bfloat16(v);
    return;
  }
  i -= 3 * 36864;
  const int n1 = CHn * 1360;
  const int n2 = CHn * 11008;
  const int n3 = CHn * (4 * 23 - 4) * 64;
  const int n4 = NTOT * (4 * 13 - 4) * 64;
  if (i < n1) {
    // X pads: rows 84..85 (all w) + cols 84..85 (h<84), 4 ch
    int c = i & 3;
    int p = (i >> 2) % 340;
    int n = (i >> 2) / 340;
    int h, w;
    if (p < 172) { h = 84 + (p / 86); w = p % 86; }
    else { int pp = p - 172; h = pp >> 1; w = 84 + (pp & 1); }
    X[(((size_t)n * 86 + h) * 86 + w) * 4 + c] = __float2bfloat16(0.f);
    return;
  }
  i -= n1;
  if (i < n2) {
    // A1 plane pads
    int ch = i & 7;
    int q = (i >> 3) % 86;
    int pl = ((i >> 3) / 86) % 16;
    int n = (i >> 3) / (86 * 16);
    const int wp = pl & 1;
    int h, w2;
    if (q < 22) { h = 0; w2 = q; }
    else if (q < 44) { h = 43; w2 = q - 22; }
    else { h = q - 43; w2 = wp ? 21 : 0; }  // h = 1..42
    A1[(size_t)n * IMG1E + pl * PLE + (h * 22 + w2) * 8 + ch] = __float2bfloat16(0.f);
    return;
  }
  i -= n2;
  if (i < n3) {
    constexpr int P = 23;
    const int RP = 4 * P - 4;
    int c = i & 63;
    int r = (i >> 6) % RP;
    int n = (i >> 6) / RP;
    int row, colp;
    if (r < P) { row = 0; colp = r; }
    else if (r < 2 * P) { row = P - 1; colp = r - P; }
    else if (r < 3 * P - 2) { row = r - 2 * P + 1; colp = 0; }
    else { row = r - (3 * P - 2) + 1; colp = P - 1; }
    A2[(((size_t)n * P + row) * P + colp) * 64 + c] = __float2bfloat16(0.f);
    return;
  }
  i -= n3;
  if (i < n4) {
    constexpr int P = 13;
    const int RP = 4 * P - 4;
    int c = i & 63;
    int r = (i >> 6) % RP;
    int n = (i >> 6) / RP;
    int row, colp;
    if (r < P) { row = 0; colp = r; }
    else if (r < 2 * P) { row = P - 1; colp = r - P; }
    else if (r < 3 * P - 2) { row = r - 2 * P + 1; colp = 0; }
    else { row = r - (3 * P - 2) + 1; colp = P - 1; }
    C3[(((size_t)n * P + row) * P + colp) * 64 + c] = __float2bfloat16(0.f);
  }
}

// ---- R26 input transform, dual-source (kept): picks xs/xt by global idx ----
__global__ void fsc_xform1b_k(const void* __restrict__ xs,
                              const void* __restrict__ xt, int g0,
                              __hip_bfloat16* __restrict__ X,
                              int n, const int* __restrict__ flag) {
  const int isf32 = *flag;
  int i = blockIdx.x * blockDim.x + threadIdx.x;
  const int imgL = i / 7056;
  if (imgL >= n) return;
  const int sp = i - imgL * 7056;
  const int h = sp / 84, w = sp - h * 84;
  const int g = g0 + imgL;
  const void* src = g < NSUP ? xs : xt;
  const size_t base = (size_t)(g < NSUP ? g : g - NSUP) * 21168;
  union { unsigned short u[4]; uint2 q; } pk;
#pragma unroll
  for (int ci = 0; ci < 3; ++ci)
    pk.u[ci] = __bfloat16_as_ushort(__float2bfloat16(load_ext(src, base + ci * 7056 + sp, isf32)));
  pk.u[3] = 0;
  *(uint2*)(void*)(X + (((size_t)imgL * 86 + h) * 86 + w) * 4) = pk.q;
}

// ---- conv1 MFMA (NHWC4 input; proven r10), epilogue -> A1 PLANE layout.
//      R14 form (8KB LDS weights) + XCD swizzle (R22). ----
__global__ void fsc_conv1m_k(const __hip_bfloat16* __restrict__ X,
                             const __hip_bfloat16* __restrict__ Wf,
                             const void* __restrict__ bias,
                             __hip_bfloat16* __restrict__ out, int N,
                             const int* __restrict__ flag) {
  __shared__ uint4 sW4[512];  // 8 KB: [s=2][t=4][lane=64][j=8] bf16
  {
    const uint4* s = (const uint4*)(const void*)Wf;
#pragma unroll
    for (int i = 0; i < 2; ++i) sW4[threadIdx.x + 256 * i] = s[threadIdx.x + 256 * i];
  }
  __syncthreads();
  const __hip_bfloat16* sW = (const __hip_bfloat16*)sW4;

  constexpr int TPI = 28;  // ceil(1764/64)
  const int wid = fsc_swz(blockIdx.x, gridDim.x) * 4 + (threadIdx.x >> 6);
  const int img = wid / TPI;
  if (img >= N) return;
  const int tl = wid - img * TPI;
  const int lane = threadIdx.x & 63;
  const int nidx = lane & 15, quad = lane >> 4;

  int col[4];
  bool val[4];
  int hoA[4], woA[4];
#pragma unroll
  for (int p = 0; p < 4; ++p) {
    col[p] = tl * 64 + p * 16 + nidx;
    val[p] = col[p] < 1764;
    if (!val[p]) col[p] = 1763;
    hoA[p] = col[p] / 42;
    woA[p] = col[p] - hoA[p] * 42;
  }

  f32x4 acc[4][4];
#pragma unroll
  for (int p = 0; p < 4; ++p)
#pragma unroll
    for (int t = 0; t < 4; ++t) acc[p][t] = (f32x4){0.f, 0.f, 0.f, 0.f};

#pragma unroll
  for (int s = 0; s < 2; ++s) {
    bf16x8 b[4];
#pragma unroll
    for (int p = 0; p < 4; ++p) {
      const int hi = 2 * hoA[p] + (s == 0 ? (quad >> 1) : 2);
      const __hip_bfloat16* bp =
          X + (((size_t)img * 86 + hi) * 86 + 2 * woA[p]) * 4 + (quad & 1) * 8;
      b[p] = *(const bf16x8*)(const void*)bp;
    }
#pragma unroll
    for (int t = 0; t < 4; ++t) {
      bf16x8 a = *(const bf16x8*)(const void*)(sW + ((size_t)(s * 4 + t) * 64 + lane) * 8);
#pragma unroll
      for (int p = 0; p < 4; ++p)
        acc[p][t] = __builtin_amdgcn_mfma_f32_16x16x32_bf16(a, b[p], acc[p][t], 0, 0, 0);
    }
  }

  const int isf32 = *flag;
#pragma unroll
  for (int p = 0; p < 4; ++p) {
    const int h = hoA[p] + 1;
    const int wq = woA[p] + 1;
    const int wp = wq & 1, w2 = wq >> 1;
#pragma unroll
    for (int t = 0; t < 4; ++t) {
      float v[4];
#pragma unroll
      for (int r = 0; r < 4; ++r) {
        const int cout = t * 16 + quad * 4 + r;
        float xv = acc[p][t][r] + load_ext(bias, cout, isf32);
        v[r] = xv > 0.f ? xv : 0.f;
      }
      if (val[p]) {
        // plane = cg*2+wp, cg = 2t + (quad>>1); within-pixel ch = (quad&1)*4
        __hip_bfloat16* o = out + (size_t)img * IMG1E +
                            ((2 * t + (quad >> 1)) * 2 + wp) * PLE +
                            (h * 22 + w2) * 8 + (quad & 1) * 4;
        union { unsigned short u[4]; uint2 w; } pk;
#pragma unroll
        for (int r = 0; r < 4; ++r) pk.u[r] = __bfloat16_as_ushort(__float2bfloat16(v[r]));
        *(uint2*)(void*)o = pk.w;
      }
    }
  }
}

// ---- conv2 from A1 planes: 32 cols x 64 couts, depth-4 B prefetch.
//      R14 form + XCD swizzle + chunk residency (proven r22-r26). ----
__global__ void fsc_conv2p_k(const __hip_bfloat16* __restrict__ A1,
                             const __hip_bfloat16* __restrict__ Wf,
                             const void* __restrict__ bias,
                             __hip_bfloat16* __restrict__ out, int N,
                             const int* __restrict__ flag) {
  __shared__ uint4 sW4[4608];  // 72 KB
  {
    const uint4* s = (const uint4*)(const void*)Wf;
#pragma unroll
    for (int i = 0; i < 18; ++i) sW4[threadIdx.x + 256 * i] = s[threadIdx.x + 256 * i];
  }
  __syncthreads();
  const __hip_bfloat16* sW = (const __hip_bfloat16*)sW4;

  constexpr int TPI = 14;  // ceil(441/32)
  const int wid = fsc_swz(blockIdx.x, gridDim.x) * 4 + (threadIdx.x >> 6);
  const int img = wid / TPI;
  if (img >= N) return;
  const int tl = wid - img * TPI;
  const int lane = threadIdx.x & 63;
  const int nidx = lane & 15, quad = lane >> 4;

  int col[2];
  bool val[2];
  int hoA[2], woA[2];
  const __hip_bfloat16* bsrc[2];
#pragma unroll
  for (int p = 0; p < 2; ++p) {
    col[p] = tl * 32 + p * 16 + nidx;
    val[p] = col[p] < 441;
    if (!val[p]) col[p] = 440;
    hoA[p] = col[p] / 21;
    woA[p] = col[p] - hoA[p] * 21;
    // base: img + quad's cg-pair + input row (2ho+1) + col w2=wo
    bsrc[p] = A1 + (size_t)img * IMG1E + quad * (2 * PLE) +
              ((2 * hoA[p] + 1) * 22 + woA[p]) * 8;
  }
  const __hip_bfloat16* asrc = sW + lane * 8;

  f32x4 acc[2][4];
#pragma unroll
  for (int p = 0; p < 2; ++p)
#pragma unroll
    for (int t = 0; t < 4; ++t) acc[p][t] = (f32x4){0.f, 0.f, 0.f, 0.f};

  // offset(kk): s=kk&1, kh=(kk>>1)/3, kw=(kk>>1)%3
#define FSC_BOFF2(kk)                                                        \
  ((((kk)&1) * 8 + ((1 + (((kk) >> 1) % 3)) & 1)) * PLE +                    \
   (((((kk) >> 1)) / 3) * 22 + ((1 + (((kk) >> 1) % 3)) >> 1)) * 8)

  bf16x8 bbuf[4][2];
#pragma unroll
  for (int d = 0; d < 3; ++d)
#pragma unroll
    for (int p = 0; p < 2; ++p)
      bbuf[d][p] = *(const bf16x8*)(const void*)(bsrc[p] + FSC_BOFF2(d));

#pragma unroll
  for (int kk = 0; kk < 18; ++kk) {
    if (kk + 3 < 18) {
#pragma unroll
      for (int p = 0; p < 2; ++p)
        bbuf[(kk + 3) & 3][p] =
            *(const bf16x8*)(const void*)(bsrc[p] + FSC_BOFF2(kk + 3));
    }
#pragma unroll
    for (int t = 0; t < 4; ++t) {
      bf16x8 a = *(const bf16x8*)(const void*)(asrc + (kk * 4 + t) * 512);
#pragma unroll
      for (int p = 0; p < 2; ++p)
        acc[p][t] =
            __builtin_amdgcn_mfma_f32_16x16x32_bf16(a, bbuf[kk & 3][p], acc[p][t], 0, 0, 0);
    }
  }
#undef FSC_BOFF2

  const int isf32 = *flag;
#pragma unroll
  for (int p = 0; p < 2; ++p) {
#pragma unroll
    for (int t = 0; t < 4; ++t) {
      float v[4];
#pragma unroll
      for (int r = 0; r < 4; ++r) {
        const int cout = t * 16 + quad * 4 + r;
        float xv = acc[p][t][r] + load_ext(bias, cout, isf32);
        v[r] = xv > 0.f ? xv : 0.f;
      }
      if (val[p]) {
        __hip_bfloat16* o = out + (((size_t)img * 23 + (hoA[p] + 1)) * 23 +
                                   (woA[p] + 1)) * 64 + t * 16 + quad * 4;
        union { unsigned short u[4]; uint2 w; } pk;
#pragma unroll
        for (int r = 0; r < 4; ++r) pk.u[r] = __bfloat16_as_ushort(__float2bfloat16(v[r]));
        *(uint2*)(void*)o = pk.w;
      }
    }
  }
}

// ---- implicit-GEMM conv, CG*16 cols x 64 couts, depth-4 B prefetch.
//      R14 form (72KB LDS) + XCD swizzle (R22). ----
template <int HO, int PWI, int PWO, int ROFF, int CG>
__global__ void fsc_convp_k(const __hip_bfloat16* __restrict__ in,
                            const __hip_bfloat16* __restrict__ Wf,
                            const void* __restrict__ bias,
                            __hip_bfloat16* __restrict__ out, int N,
                            const int* __restrict__ flag) {
  __shared__ uint4 sW4[4608];  // 72 KB
  {
    const uint4* s = (const uint4*)(const void*)Wf;
#pragma unroll
    for (int i = 0; i < 18; ++i) sW4[threadIdx.x + 256 * i] = s[threadIdx.x + 256 * i];
  }
  __syncthreads();
  const __hip_bfloat16* sW = (const __hip_bfloat16*)sW4;

  constexpr int COLS = CG * 16;
  constexpr int TPI = (HO * HO + COLS - 1) / COLS;
  const int wid = fsc_swz(blockIdx.x, gridDim.x) * 4 + (threadIdx.x >> 6);
  const int img = wid / TPI;
  if (img >= N) return;
  const int tl = wid - img * TPI;
  const int lane = threadIdx.x & 63;
  const int nidx = lane & 15, quad = lane >> 4;

  int col[CG];
  bool val[CG];
  int hoA[CG], woA[CG];
  const __hip_bfloat16* bsrc[CG];
#pragma unroll
  for (int p = 0; p < CG; ++p) {
    col[p] = tl * COLS + p * 16 + nidx;
    val[p] = col[p] < HO * HO;
    if (!val[p]) col[p] = HO * HO - 1;
    hoA[p] = col[p] / HO;
    woA[p] = col[p] - hoA[p] * HO;
    bsrc[p] = in + (((size_t)img * PWI + (2 * hoA[p] + ROFF)) * PWI +
                    (2 * woA[p] + ROFF)) * 64 + quad * 8;
  }
  const __hip_bfloat16* asrc = sW + lane * 8;

  f32x4 acc[CG][4];
#pragma unroll
  for (int p = 0; p < CG; ++p)
#pragma unroll
    for (int t = 0; t < 4; ++t) acc[p][t] = (f32x4){0.f, 0.f, 0.f, 0.f};

#define FSC_BOFF(kk) ((((kk) >> 1) / 3 * PWI + ((kk) >> 1) % 3) * 64 + ((kk)&1) * 32)

  bf16x8 bbuf[4][CG];
#pragma unroll
  for (int d = 0; d < 3; ++d)
#pragma unroll
    for (int p = 0; p < CG; ++p)
      bbuf[d][p] = *(const bf16x8*)(const void*)(bsrc[p] + FSC_BOFF(d));

#pragma unroll
  for (int kk = 0; kk < 18; ++kk) {
    if (kk + 3 < 18) {
#pragma unroll
      for (int p = 0; p < CG; ++p)
        bbuf[(kk + 3) & 3][p] =
            *(const bf16x8*)(const void*)(bsrc[p] + FSC_BOFF(kk + 3));
    }
#pragma unroll
    for (int t = 0; t < 4; ++t) {
      bf16x8 a = *(const bf16x8*)(const void*)(asrc + (kk * 4 + t) * 512);
#pragma unroll
      for (int p = 0; p < CG; ++p)
        acc[p][t] =
            __builtin_amdgcn_mfma_f32_16x16x32_bf16(a, bbuf[kk & 3][p], acc[p][t], 0, 0, 0);
    }
  }
#undef FSC_BOFF

  const int isf32 = *flag;
#pragma unroll
  for (int p = 0; p < CG; ++p) {
#pragma unroll
    for (int t = 0; t < 4; ++t) {
      float v[4];
#pragma unroll
      for (int r = 0; r < 4; ++r) {
        const int cout = t * 16 + quad * 4 + r;
        float xv = acc[p][t][r] + load_ext(bias, cout, isf32);
        v[r] = xv > 0.f ? xv : 0.f;
      }
      if (val[p]) {
        __hip_bfloat16* o = out + (((size_t)img * PWO + (hoA[p] + 1)) * PWO +
                                   (woA[p] + 1)) * 64 + t * 16 + quad * 4;
        union { unsigned short u[4]; uint2 w; } pk;
#pragma unroll
        for (int r = 0; r < 4; ++r) pk.u[r] = __bfloat16_as_ushort(__float2bfloat16(v[r]));
        *(uint2*)(void*)o = pk.w;
      }
    }
  }
}

// ---- 32-col MFMA conv, EMB output (conv4). R14 form + XCD swizzle. ----
__global__ void fsc_conv4_k(const __hip_bfloat16* __restrict__ in,
                            const __hip_bfloat16* __restrict__ Wf,
                            const void* __restrict__ bias, float* __restrict__ emb,
                            int N, const int* __restrict__ flag) {
  __shared__ uint4 sW4[4608];  // 72 KB
  {
    const uint4* s = (const uint4*)(const void*)Wf;
#pragma unroll
    for (int i = 0; i < 18; ++i) sW4[threadIdx.x + 256 * i] = s[threadIdx.x + 256 * i];
  }
  __syncthreads();
  const __hip_bfloat16* sW = (const __hip_bfloat16*)sW4;

  constexpr int HO = 6, PWI = 13;
  constexpr int TPI = 2;  // ceil(36/32)
  const int wid = fsc_swz(blockIdx.x, gridDim.x) * 4 + (threadIdx.x >> 6);
  const int img = wid / TPI;
  if (img >= N) return;
  const int tl = wid - img * TPI;
  const int lane = threadIdx.x & 63;
  const int nidx = lane & 15, quad = lane >> 4;

  int col0 = tl * 32 + nidx;
  int col1 = col0 + 16;
  const bool val0 = col0 < HO * HO;
  const bool val1 = col1 < HO * HO;
  if (!val0) col0 = HO * HO - 1;
  if (!val1) col1 = HO * HO - 1;
  const int ho0 = col0 / HO, wo0 = col0 - ho0 * HO;
  const int ho1 = col1 / HO, wo1 = col1 - ho1 * HO;

  const __hip_bfloat16* bsrc0 =
      in + (((size_t)img * PWI + 2 * ho0) * PWI + 2 * wo0) * 64 + quad * 8;
  const __hip_bfloat16* bsrc1 =
      in + (((size_t)img * PWI + 2 * ho1) * PWI + 2 * wo1) * 64 + quad * 8;
  const __hip_bfloat16* asrc = sW + lane * 8;

  f32x4 acc[2][4];
#pragma unroll
  for (int p = 0; p < 2; ++p)
#pragma unroll
    for (int t = 0; t < 4; ++t) acc[p][t] = (f32x4){0.f, 0.f, 0.f, 0.f};

#pragma unroll
  for (int kk = 0; kk < 18; ++kk) {
    const int s = kk & 1;
    const int khw = kk >> 1;
    const int kh = khw / 3, kw = khw - kh * 3;
    const int boff = (kh * PWI + kw) * 64 + s * 32;
    bf16x8 b0 = *(const bf16x8*)(const void*)(bsrc0 + boff);
    bf16x8 b1 = *(const bf16x8*)(const void*)(bsrc1 + boff);
#pragma unroll
    for (int t = 0; t < 4; ++t) {
      bf16x8 a = *(const bf16x8*)(const void*)(asrc + (kk * 4 + t) * 512);
      acc[0][t] = __builtin_amdgcn_mfma_f32_16x16x32_bf16(a, b0, acc[0][t], 0, 0, 0);
      acc[1][t] = __builtin_amdgcn_mfma_f32_16x16x32_bf16(a, b1, acc[1][t], 0, 0, 0);
    }
  }

  const int isf32 = *flag;
#pragma unroll
  for (int p = 0; p < 2; ++p) {
    const bool valid = p == 0 ? val0 : val1;
    const int col = p == 0 ? col0 : col1;
#pragma unroll
    for (int t = 0; t < 4; ++t) {
      float v[4];
#pragma unroll
      for (int r = 0; r < 4; ++r) {
        const int cout = t * 16 + quad * 4 + r;
        float xv = acc[p][t][r] + load_ext(bias, cout, isf32);
        v[r] = xv > 0.f ? xv : 0.f;
      }
      if (valid) {
        float* o = emb + ((size_t)img * 36 + col) * 64 + t * 16 + quad * 4;
        *(f32x4*)(void*)o = (f32x4){v[0], v[1], v[2], v[3]};
      }
    }
  }
}

// ---- head: R25 form (separate proto/pnorm — 360/40 blocks; proven) ----
__global__ void fsc_proto_k(const float* __restrict__ emb_s, const int* __restrict__ y,
                            float* __restrict__ protos) {
  int i = blockIdx.x * blockDim.x + threadIdx.x;
  if (i >= BB * CC * DD) return;
  int d = i % DD;
  int bc = i / DD;
  int c = bc % CC;
  int b = bc / CC;
  float sum = 0.f;
  for (int s = 0; s < SS; ++s) {
    if (y[b * SS + s] % CC == c) sum += emb_s[(size_t)(b * SS + s) * DD + d];
  }
  protos[i] = sum * 0.2f;
}

__global__ void fsc_pnorm_k(const float* __restrict__ protos, float* __restrict__ pn) {
  __shared__ float red[4];
  __shared__ float inv;
  const int bc = blockIdx.x;
  const float* p = protos + (size_t)bc * DD;
  float ss = 0.f;
  for (int d = threadIdx.x; d < DD; d += 256) { float v = p[d]; ss += v * v; }
#pragma unroll
  for (int off = 32; off > 0; off >>= 1) ss += __shfl_down(ss, off);
  if ((threadIdx.x & 63) == 0) red[threadIdx.x >> 6] = ss;
  __syncthreads();
  if (threadIdx.x == 0) {
    float nrm = sqrtf(red[0] + red[1] + red[2] + red[3]);
    nrm = nrm > EPSF ? nrm : EPSF;
    inv = 1.f / nrm;
  }
  __syncthreads();
  float sc = inv;
  for (int d = threadIdx.x; d < DD; d += 256) pn[(size_t)bc * DD + d] = p[d] * sc;
}

__global__ void fsc_preds_k(const float* __restrict__ emb_t, const float* __restrict__ pn,
                            void* __restrict__ out, const int* __restrict__ flag) {
  __shared__ float red[4][6];
  __shared__ float fin[6];
  const int isf32 = *flag;
  const int bt = blockIdx.x;
  const int b = bt / TT;
  const float* et = emb_t + (size_t)bt * DD;
  float e[9];
#pragma unroll
  for (int k = 0; k < 9; ++k) e[k] = et[threadIdx.x + 256 * k];
  float vals[6];
  {
    float ss = 0.f;
#pragma unroll
    for (int k = 0; k < 9; ++k) ss += e[k] * e[k];
    vals[0] = ss;
  }
  const float* pb = pn + (size_t)b * CC * DD;
#pragma unroll
  for (int c = 0; c < CC; ++c) {
    float s = 0.f;
#pragma unroll
    for (int k = 0; k < 9; ++k) s += e[k] * pb[(size_t)c * DD + threadIdx.x + 256 * k];
    vals[1 + c] = s;
  }
#pragma unroll
  for (int v = 0; v < 6; ++v) {
#pragma unroll
    for (int off = 32; off > 0; off >>= 1) vals[v] += __shfl_down(vals[v], off);
  }
  if ((threadIdx.x & 63) == 0) {
#pragma unroll
    for (int v = 0; v < 6; ++v) red[threadIdx.x >> 6][v] = vals[v];
  }
  __syncthreads();
  if (threadIdx.x < 6)
    fin[threadIdx.x] = red[0][threadIdx.x] + red[1][threadIdx.x] +
                       red[2][threadIdx.x] + red[3][threadIdx.x];
  __syncthreads();
  if (threadIdx.x < CC) {
    float nt = sqrtf(fin[0]);
    nt = nt > EPSF ? nt : EPSF;
    float r = fin[1 + threadIdx.x] / nt;
    if (isf32) ((float*)out)[(size_t)bt * CC + threadIdx.x] = r;
    else ((__hip_bfloat16*)out)[(size_t)bt * CC + threadIdx.x] = __float2bfloat16(r);
  }
}

static inline int fsc_cdiv(int a, int b) { return (a + b - 1) / b; }
static inline int imin(int a, int b) { return a < b ? a : b; }

extern "C" void kernel_launch(void* const* d_in, const int* in_sizes, int n_in,
                              void* d_out, int out_size, void* d_ws, size_t ws_size,
                              hipStream_t stream) {
  const void* xs = d_in[0];
  const void* xt = d_in[1];
  const int* y = (const int*)d_in[2];
  const void* W1 = d_in[3];
  const void* b1 = d_in[4];
  const void* W2 = d_in[5];
  const void* b2 = d_in[6];
  const void* W3 = d_in[7];
  const void* b3 = d_in[8];
  const void* W4 = d_in[9];
  const void* b4 = d_in[10];

  // ---- workspace layout: fixed ~25.6 MB + X/A1/A2 chunk buffers ----
  char* w = (char*)d_ws;
  int* flag = (int*)w;                      w += 256;
  __hip_bfloat16* Wf1 = (__hip_bfloat16*)w; w += 4096 * 2;
  __hip_bfloat16* Wf2 = (__hip_bfloat16*)w; w += 36864 * 2;
  __hip_bfloat16* Wf3 = (__hip_bfloat16*)w; w += 36864 * 2;
  __hip_bfloat16* Wf4 = (__hip_bfloat16*)w; w += 36864 * 2;
  float* protos = (float*)w;                w += (size_t)BB * CC * DD * 4;
  float* pn = (float*)w;                    w += (size_t)BB * CC * DD * 4;
  float* emb = (float*)w;                   w += (size_t)NTOT * DD * 4;           // 7.37 MB
  __hip_bfloat16* C3 = (__hip_bfloat16*)w;  w += (size_t)NTOT * 13 * 13 * 64 * 2; // 17.3 MB
  char* chunk0 = w;
  const size_t fixedB = (size_t)(w - (char*)d_ws);
  const size_t szX  = (size_t)86 * 86 * 4 * 2;    //  59,168 B/img
  const size_t szA1 = (size_t)IMG1E * 2;          // 247,808 B/img (plane layout)
  const size_t szA2 = (size_t)23 * 23 * 64 * 2;   //  67,712 B/img
  const size_t perImgB = szX + szA1 + szA2;        // 374,688 B/img

  // CH=400 (R24): residency + grid fill interior optimum.
  int CH = 50;
  const int cands[4] = {400, 200, 100, 50};
  for (int k = 0; k < 4; ++k) {
    if (fixedB + (size_t)cands[k] * perImgB <= ws_size) { CH = cands[k]; break; }
  }
  __hip_bfloat16* X  = (__hip_bfloat16*)chunk0;
  __hip_bfloat16* A1 = (__hip_bfloat16*)(chunk0 + (size_t)CH * szX);
  __hip_bfloat16* A2 = (__hip_bfloat16*)(chunk0 + (size_t)CH * (szX + szA1));

  // 1. dtype probe + setup mega-kernel (repacks + pad zeroing merged)
  fsc_probe_dtype_k<<<1, 256, 0, stream>>>((const unsigned short*)W2, 64 * 64 * 9, flag);
  {
    const int nz = 4096 + 3 * 36864 + CH * 1360 + CH * 11008 +
                   CH * (4 * 23 - 4) * 64 + NTOT * (4 * 13 - 4) * 64;
    fsc_setup_k<<<fsc_cdiv(nz, 256), 256, 0, stream>>>(
        W1, W2, W3, W4, Wf1, Wf2, Wf3, Wf4, X, A1, A2, C3, CH, flag);
  }

  // 2. chunks over GLOBAL image index (support 0..199, target 200..799)
  for (int g0 = 0; g0 < NTOT; g0 += CH) {
    const int n = imin(CH, NTOT - g0);
    // input transform (dual-source, one call per chunk)
    fsc_xform1b_k<<<fsc_cdiv(n * 7056, 256), 256, 0, stream>>>(
        xs, xt, g0, X, n, flag);
    // conv1: NHWC4 -> A1 planes; TPI=28
    fsc_conv1m_k<<<fsc_cdiv(n * 28, 4), 256, 0, stream>>>(X, Wf1, b1, A1, n, flag);
    // conv2: A1 planes -> 21x21 into 23-pad NHWC; 32 cols (TPI=14)
    fsc_conv2p_k<<<fsc_cdiv(n * 14, 4), 256, 0, stream>>>(A1, Wf2, b2, A2, n, flag);
    // conv3: 23-pad -> 11x11 into 13-pad; ROFF=0; 16 cols (TPI=8)
    fsc_convp_k<11, 23, 13, 0, 1><<<fsc_cdiv(n * 8, 4), 256, 0, stream>>>(
        A2, Wf3, b3, C3 + (size_t)g0 * 13 * 13 * 64, n, flag);
  }

  // 3. conv4 full batch: 13-pad -> fp32 emb [800][2304]
  fsc_conv4_k<<<fsc_cdiv(NTOT * 2, 4), 256, 0, stream>>>(C3, Wf4, b4, emb, NTOT, flag);

  // 4. head (R25 form: separate proto + pnorm, full occupancy)
  fsc_proto_k<<<fsc_cdiv(BB * CC * DD, 256), 256, 0, stream>>>(emb, y, protos);
  fsc_pnorm_k<<<BB * CC, 256, 0, stream>>>(protos, pn);
  fsc_preds_k<<<NTGT, 256, 0, stream>>>(emb + (size_t)NSUP * DD, pn, d_out, flag);
}